// Round 3
// baseline (404894.019 us; speedup 1.0000x reference)
//
#include <hip/hip_runtime.h>

#define NB 128    // batch == grid
#define NT 256    // threads per block
#define TT 1024   // time steps
#define DI 64     // input dim
#define DH 512    // hidden dim
#define DB 128    // backbone units

typedef unsigned short u16;
typedef unsigned int u32;
typedef unsigned long long u64;

__device__ __forceinline__ float bf2f(u16 u) {
  union { u32 i; float f; } v; v.i = ((u32)u) << 16; return v.f;
}
__device__ __forceinline__ u16 f2bf_rne(float x) {
  union { float f; u32 i; } v; v.f = x;
  return (u16)((v.i + 0x7fffu + ((v.i >> 16) & 1u)) >> 16);
}
__device__ __forceinline__ float fsig(float x) {
  return __builtin_amdgcn_rcpf(1.f + __expf(-x));
}
__device__ __forceinline__ float ftanh(float x) {
  return 1.f - 2.f * __builtin_amdgcn_rcpf(__expf(2.f * x) + 1.f);
}
// 8 bf16 (one uint4) FMA'd against 8 fp32 values into acc
__device__ __forceinline__ void fma8(float& acc, const uint4 u, const float* v) {
  union { u32 i; float f; } t;
  t.i = u.x << 16;          acc = fmaf(t.f, v[0], acc);
  t.i = u.x & 0xffff0000u;  acc = fmaf(t.f, v[1], acc);
  t.i = u.y << 16;          acc = fmaf(t.f, v[2], acc);
  t.i = u.y & 0xffff0000u;  acc = fmaf(t.f, v[3], acc);
  t.i = u.z << 16;          acc = fmaf(t.f, v[4], acc);
  t.i = u.z & 0xffff0000u;  acc = fmaf(t.f, v[5], acc);
  t.i = u.w << 16;          acc = fmaf(t.f, v[6], acc);
  t.i = u.w & 0xffff0000u;  acc = fmaf(t.f, v[7], acc);
}

// ---------------- dtype detection (device-side, graph-safe) ----------------
// Genuine bf16 tensors from these distributions have exponent field < 134 on
// every element. If the buffer is really f32, even u16 indices are f32 low
// halves = uniform random mantissa bits (sane-rate ~52%). 192 samples at a
// 180 threshold => misdetection probability ~1e-18.
__global__ void detect_kernel(const u16* x, const u16* wi, const u16* wh, int* flag) {
  const int l = threadIdx.x;  // 0..63
  int cnt = (((x[2 * l] >> 7) & 0xFF) < 134)
          + (((wi[2 * l] >> 7) & 0xFF) < 134)
          + (((wh[2 * l] >> 7) & 0xFF) < 134);
#pragma unroll
  for (int off = 32; off > 0; off >>= 1) cnt += __shfl_down(cnt, off, 64);
  if (l == 0) *flag = (cnt >= 180) ? 1 : 0;  // 1 = already bf16
}

// ------------- normalize all inputs to bf16 in the workspace ---------------
struct ConvArgs {
  const void* src[16];
  u32 n[16];
  u32 off[16];  // destination offset in u16 elements
};

__global__ void convert_kernel(ConvArgs a, const int* __restrict__ flag,
                               u16* __restrict__ dst) {
  const int b = blockIdx.y;
  const u32 n = a.n[b];
  u16* d = dst + a.off[b];
  const u32 stride = gridDim.x * blockDim.x;
  const u32 i0 = blockIdx.x * blockDim.x + threadIdx.x;
  if (*flag) {
    const u16* s = (const u16*)a.src[b];
    for (u32 i = i0; i < n; i += stride) d[i] = s[i];
  } else {
    const float* s = (const float*)a.src[b];
    for (u32 i = i0; i < n; i += stride) d[i] = f2bf_rne(s[i]);
  }
}

// ------------------------------ main scan ----------------------------------
__global__ __launch_bounds__(NT, 1)
void cfc_scan_kernel(const u16* __restrict__ x,   const u16* __restrict__ Wi,
                     const u16* __restrict__ bi,  const u16* __restrict__ Wh,
                     const u16* __restrict__ bbW, const u16* __restrict__ bbb,
                     const u16* __restrict__ f1W, const u16* __restrict__ f1b,
                     const u16* __restrict__ f2W, const u16* __restrict__ f2b,
                     const u16* __restrict__ taW, const u16* __restrict__ tab,
                     const u16* __restrict__ tbW, const u16* __restrict__ tbb,
                     const u16* __restrict__ hW,  const u16* __restrict__ hb,
                     float* __restrict__ out)     // f32 output per reference
{
  __shared__ __align__(16) float vcat[DI + DH];  // [x_t | h_lstm]
  __shared__ __align__(16) float hprev[DH];
  __shared__ __align__(16) float Fb[DB];
  __shared__ __align__(16) float fpart[NT];

  const int j = threadIdx.x;
  const int b = blockIdx.x;
  const int u0 = j, u1 = j + 256;

  float bi_r[8];
#pragma unroll
  for (int k = 0; k < 8; ++k) bi_r[k] = bf2f(bi[j + 256 * k]);
  const float b_f1_0 = bf2f(f1b[u0]), b_f1_1 = bf2f(f1b[u1]);
  const float b_f2_0 = bf2f(f2b[u0]), b_f2_1 = bf2f(f2b[u1]);
  const float b_ta_0 = bf2f(tab[u0]), b_ta_1 = bf2f(tab[u1]);
  const float b_tb_0 = bf2f(tbb[u0]), b_tb_1 = bf2f(tbb[u1]);
  const float b_bb   = (j < DB) ? bf2f(bbb[j]) : 0.f;

  float hwr[8]; float hbr = 0.f;
  if (j < 128) {
    const int w = j >> 6, l = j & 63;
#pragma unroll
    for (int q = 0; q < 8; ++q) hwr[q] = bf2f(hW[w * DH + q * 64 + l]);
    hbr = bf2f(hb[w]);
  }

  float c0 = 0.f, c1 = 0.f;
  hprev[u0] = 0.f; hprev[u1] = 0.f;
  const u16* xp = x + (size_t)b * TT * DI;

  __syncthreads();

  for (int t = 0; t < TT; ++t) {
    if (j < DI) vcat[j] = bf2f(xp[t * DI + j]);
    __syncthreads();

    // z = bi + x@Wi^T + h@Wh^T
    float a[8];
#pragma unroll
    for (int k = 0; k < 8; ++k) a[k] = bi_r[k];

#pragma unroll
    for (int r = 0; r < 8; ++r) {
      const u16* wr = Wi + ((size_t)(j + 256 * r)) * DI;
      float acc = a[r];
#pragma unroll
      for (int kk = 0; kk < DI; kk += 8) {
        uint4 u = *(const uint4*)(wr + kk);
        fma8(acc, u, vcat + kk);
      }
      a[r] = acc;
    }

#pragma unroll 1
    for (int kb = 0; kb < DH; kb += 64) {
      float hreg[64];
#pragma unroll
      for (int q = 0; q < 16; ++q)
        *(float4*)(hreg + 4 * q) = *(const float4*)(hprev + kb + 4 * q);
#pragma unroll
      for (int r = 0; r < 8; ++r) {
        const u16* wr = Wh + ((size_t)(j + 256 * r)) * DH + kb;
        float acc = a[r];
#pragma unroll
        for (int c = 0; c < 8; ++c) {
          uint4 u = *(const uint4*)(wr + 8 * c);
          fma8(acc, u, hreg + 8 * c);
        }
        a[r] = acc;
      }
    }

    // LSTM gates: i=a[0,1] ig=a[2,3] fg=a[4,5] og=a[6,7]
    {
      const float cn0 = fmaf(c0, fsig(a[4] + 1.f), ftanh(a[0]) * fsig(a[2]));
      const float cn1 = fmaf(c1, fsig(a[5] + 1.f), ftanh(a[1]) * fsig(a[3]));
      c0 = cn0; c1 = cn1;
      vcat[DI + u0] = ftanh(cn0) * fsig(a[6]);
      vcat[DI + u1] = ftanh(cn1) * fsig(a[7]);
    }
    __syncthreads();

    // backbone: F = lecun_tanh(bb_b + [x|h_lstm] @ bbW^T), 2-way K split
    {
      const int m = j & (DB - 1), p = j >> 7;
      const u16* br = bbW + (size_t)m * (DI + DH) + p * 288;
      const float* vs = vcat + p * 288;
      float s0 = 0.f, s1 = 0.f, s2 = 0.f, s3 = 0.f;
#pragma unroll
      for (int kk = 0; kk < 288; kk += 32) {
        fma8(s0, *(const uint4*)(br + kk),      vs + kk);
        fma8(s1, *(const uint4*)(br + kk + 8),  vs + kk + 8);
        fma8(s2, *(const uint4*)(br + kk + 16), vs + kk + 16);
        fma8(s3, *(const uint4*)(br + kk + 24), vs + kk + 24);
      }
      fpart[j] = (s0 + s1) + (s2 + s3);
    }
    __syncthreads();
    if (j < DB) Fb[j] = 1.7159f * ftanh(0.666f * (b_bb + fpart[j] + fpart[j + DB]));
    __syncthreads();

    // ff1/ff2/time_a/time_b (K=128) + interpolation
    {
      float Fr[DB];
#pragma unroll
      for (int q = 0; q < 32; ++q)
        *(float4*)(Fr + 4 * q) = *(const float4*)(Fb + 4 * q);

      const u16* rp[8] = {
        f1W + (size_t)u0 * DB, f1W + (size_t)u1 * DB,
        f2W + (size_t)u0 * DB, f2W + (size_t)u1 * DB,
        taW + (size_t)u0 * DB, taW + (size_t)u1 * DB,
        tbW + (size_t)u0 * DB, tbW + (size_t)u1 * DB };
      float sacc[8] = { b_f1_0, b_f1_1, b_f2_0, b_f2_1,
                        b_ta_0, b_ta_1, b_tb_0, b_tb_1 };
#pragma unroll
      for (int rr = 0; rr < 8; ++rr) {
        float acc = sacc[rr];
        const u16* r = rp[rr];
#pragma unroll
        for (int kk = 0; kk < DB; kk += 8)
          fma8(acc, *(const uint4*)(r + kk), Fr + kk);
        sacc[rr] = acc;
      }
      const float ti0 = fsig(sacc[4] + sacc[6]);
      const float ti1 = fsig(sacc[5] + sacc[7]);
      const float hn0 = fmaf(ftanh(sacc[0]), 1.f - ti0, ti0 * ftanh(sacc[2]));
      const float hn1 = fmaf(ftanh(sacc[1]), 1.f - ti1, ti1 * ftanh(sacc[3]));
      hprev[u0] = hn0; hprev[u1] = hn1;
    }
    __syncthreads();

    // physics head: 2 outputs, waves 0/1, 64-lane shuffle reduce
    if (j < 128) {
      const int l = j & 63;
      float acc = 0.f;
#pragma unroll
      for (int q = 0; q < 8; ++q) acc = fmaf(hprev[q * 64 + l], hwr[q], acc);
#pragma unroll
      for (int off = 32; off > 0; off >>= 1) acc += __shfl_down(acc, off, 64);
      if (l == 0) out[((size_t)b * TT + t) * 2 + (j >> 6)] = acc + hbr;
    }
  }

  out[(size_t)NB * TT * 2 + (size_t)b * DH + u0] = hprev[u0];
  out[(size_t)NB * TT * 2 + (size_t)b * DH + u1] = hprev[u1];
}

extern "C" void kernel_launch(void* const* d_in, const int* in_sizes, int n_in,
                              void* d_out, int out_size, void* d_ws, size_t ws_size,
                              hipStream_t stream) {
  (void)n_in; (void)out_size;

  // workspace layout: [64B flag][16 bf16 buffers, 64B-aligned]
  int* flag = (int*)d_ws;
  u16* wsd = (u16*)((char*)d_ws + 64);

  ConvArgs a;
  u64 cur = 0;
  for (int i = 0; i < 16; ++i) {
    a.src[i] = d_in[i];
    a.n[i]   = (u32)in_sizes[i];
    a.off[i] = (u32)cur;
    cur += ((u64)in_sizes[i] + 31) & ~31ull;  // 64B-aligned regions
  }
  const u64 need = 64 + 2 * cur;

  const u16* p[16];
  if (ws_size >= need) {
    // adaptive path: detect dtype, normalize everything to bf16 in ws
    detect_kernel<<<dim3(1), dim3(64), 0, stream>>>(
        (const u16*)d_in[0], (const u16*)d_in[1], (const u16*)d_in[3], flag);
    convert_kernel<<<dim3(1024, 16), dim3(256), 0, stream>>>(a, flag, wsd);
    for (int i = 0; i < 16; ++i) p[i] = wsd + a.off[i];
  } else {
    // fallback: assume buffers are already bf16
    for (int i = 0; i < 16; ++i) p[i] = (const u16*)d_in[i];
  }

  cfc_scan_kernel<<<dim3(NB), dim3(NT), 0, stream>>>(
      p[0], p[1], p[2], p[3], p[4], p[5], p[6], p[7],
      p[8], p[9], p[10], p[11], p[12], p[13], p[14], p[15],
      (float*)d_out);
}

// Round 4
// 24426.538 us; speedup vs baseline: 16.5760x; 16.5760x over previous
//
#include <hip/hip_runtime.h>

#define NB 128
#define NT 1024
#define TT 1024
#define DI 64
#define DH 512
#define DB 128
#define GZ 2048          // 4*DH gate rows
#define KZ 576           // DI+DH

typedef unsigned short u16;
typedef unsigned int u32;
typedef unsigned long long u64;

// ---- ws byte offsets (all 256-aligned) ----
#define O_X      256
#define SZ_X     (NB*TT*DI*2)            // 16,777,216
#define O_BI     (O_X + SZ_X)
#define O_BBB    (O_BI + 4096)
#define O_F1B    (O_BBB + 256)
#define O_F2B    (O_F1B + 1024)
#define O_TAB    (O_F2B + 1024)
#define O_TBB    (O_TAB + 1024)
#define O_HW     (O_TBB + 1024)
#define O_HB     (O_HW + 2048)
#define O_WZT    (O_HB + 256)
#define SZ_WZT   (KZ*GZ*2)               // 2,359,296
#define O_BBT    (O_WZT + SZ_WZT)
#define SZ_BBT   (288*128*4)             // 147,456
#define O_FFT    (O_BBT + SZ_BBT)
#define SZ_FFT   (4*128*512*2)           // 524,288
#define WS_NEED  ((u64)(O_FFT + SZ_FFT)) // ~19.8 MB

__device__ __forceinline__ float bf2f(u16 u) {
  union { u32 i; float f; } v; v.i = ((u32)u) << 16; return v.f;
}
__device__ __forceinline__ u16 f2bf_rne(float x) {
  union { float f; u32 i; } v; v.f = x;
  return (u16)((v.i + 0x7fffu + ((v.i >> 16) & 1u)) >> 16);
}
__device__ __forceinline__ float blo(u32 w) {
  union { u32 i; float f; } v; v.i = w << 16; return v.f;
}
__device__ __forceinline__ float bhi(u32 w) {
  union { u32 i; float f; } v; v.i = w & 0xffff0000u; return v.f;
}
__device__ __forceinline__ float fsig(float x) {
  return __builtin_amdgcn_rcpf(1.f + __expf(-x));
}
__device__ __forceinline__ float ftanh(float x) {
  return 1.f - 2.f * __builtin_amdgcn_rcpf(__expf(2.f * x) + 1.f);
}

// ---------------- dtype detection (validated in round 3) ----------------
__global__ void detect_kernel(const u16* x, const u16* wi, const u16* wh, int* flag) {
  const int l = threadIdx.x;
  int cnt = (((x[2 * l] >> 7) & 0xFF) < 134)
          + (((wi[2 * l] >> 7) & 0xFF) < 134)
          + (((wh[2 * l] >> 7) & 0xFF) < 134);
#pragma unroll
  for (int off = 32; off > 0; off >>= 1) cnt += __shfl_down(cnt, off, 64);
  if (l == 0) *flag = (cnt >= 180) ? 1 : 0;  // 1 = already bf16
}

// ------- copy/convert x + bias/head vectors into ws (bf16) -------
struct CopyArgs {
  const void* src[9];
  u16* dst[9];
  u32 n[9];
};
__global__ void conv_kernel(CopyArgs a, const int* __restrict__ flag) {
  const int bidx = blockIdx.y;
  const u32 n = a.n[bidx];
  u16* d = a.dst[bidx];
  const u32 stride = gridDim.x * blockDim.x;
  const u32 i0 = blockIdx.x * blockDim.x + threadIdx.x;
  if (*flag) {
    const u16* s = (const u16*)a.src[bidx];
    for (u32 i = i0; i < n; i += stride) d[i] = s[i];
  } else {
    const float* s = (const float*)a.src[bidx];
    for (u32 i = i0; i < n; i += stride) d[i] = f2bf_rne(s[i]);
  }
}

// ------- transposes: WzT[k][o] = k<64 ? Wi[o][k] : Wh[o][k-64] -------
__global__ void t_wz(const void* Wi, const void* Wh, const int* __restrict__ flag,
                     u16* __restrict__ dst) {
  const int o = blockIdx.x * 256 + threadIdx.x;   // 0..2047
  const int k = blockIdx.y;                       // 0..575
  const u32 idx = (k < DI) ? (u32)(o * DI + k) : (u32)(o * DH + (k - DI));
  const void* s = (k < DI) ? Wi : Wh;
  u16 v = (*flag) ? ((const u16*)s)[idx] : f2bf_rne(((const float*)s)[idx]);
  dst[k * GZ + o] = v;
}
// bbT[k2][m] packs k=2k2 (lo) and k=2k2+1 (hi) of bbW[m][:]
__global__ void t_bb(const void* bb, const int* __restrict__ flag,
                     u32* __restrict__ dst) {
  const int m = threadIdx.x;        // 0..127
  const int k2 = blockIdx.x;        // 0..287
  u16 lo, hi;
  if (*flag) {
    const u16* s = (const u16*)bb;
    lo = s[m * KZ + 2 * k2]; hi = s[m * KZ + 2 * k2 + 1];
  } else {
    const float* s = (const float*)bb;
    lo = f2bf_rne(s[m * KZ + 2 * k2]); hi = f2bf_rne(s[m * KZ + 2 * k2 + 1]);
  }
  dst[k2 * DB + m] = (u32)lo | ((u32)hi << 16);
}
// ffT[mat][k][o] = Wmat[o][k]
__global__ void t_ff(const void* f1, const void* f2, const void* ta, const void* tb,
                     const int* __restrict__ flag, u16* __restrict__ dst) {
  const int o = blockIdx.x * 256 + threadIdx.x;   // 0..511
  const int k = blockIdx.y;                       // 0..127
  const int mat = blockIdx.z;                     // 0..3
  const void* s = (mat == 0) ? f1 : (mat == 1) ? f2 : (mat == 2) ? ta : tb;
  const u32 idx = (u32)(o * DB + k);
  u16 v = (*flag) ? ((const u16*)s)[idx] : f2bf_rne(((const float*)s)[idx]);
  dst[mat * (DB * DH) + k * DH + o] = v;
}

__device__ __forceinline__ void fma8b(const uint4 u, float hk,
    float& a0, float& a1, float& a2, float& a3,
    float& a4, float& a5, float& a6, float& a7) {
  a0 = fmaf(blo(u.x), hk, a0); a1 = fmaf(bhi(u.x), hk, a1);
  a2 = fmaf(blo(u.y), hk, a2); a3 = fmaf(bhi(u.y), hk, a3);
  a4 = fmaf(blo(u.z), hk, a4); a5 = fmaf(bhi(u.z), hk, a5);
  a6 = fmaf(blo(u.w), hk, a6); a7 = fmaf(bhi(u.w), hk, a7);
}

// ------------------------------ main scan ------------------------------
__global__ __launch_bounds__(NT)
void scan_main(const u16* __restrict__ xw,  const u16* __restrict__ WzT,
               const u32* __restrict__ bbT, const u16* __restrict__ ffT,
               const u16* __restrict__ biA, const u16* __restrict__ bbbA,
               const u16* __restrict__ f1bA, const u16* __restrict__ f2bA,
               const u16* __restrict__ tabA, const u16* __restrict__ tbbA,
               const u16* __restrict__ hWA,  const u16* __restrict__ hbA,
               float* __restrict__ out)
{
  __shared__ __align__(16) float zin[KZ];      // [x_t | h]        (Z input)
  __shared__ __align__(16) float vcat[KZ];     // [x_t | h_lstm]   (BB input)
  __shared__ __align__(16) float zred[4 * GZ]; // Z k-slice partials (32 KB)
  __shared__ __align__(16) float bbred[8 * DB];
  __shared__ __align__(16) float Fb[DB];
  __shared__ __align__(16) float zff[4 * DH];

  const int j = threadIdx.x;
  const int b = blockIdx.x;
  const int u = j & (DH - 1);

  // hoisted constants
  float bi0 = 0.f, bi1 = 0.f, bi2 = 0.f, bi3 = 0.f, c = 0.f;
  if (j < DH) {
    bi0 = bf2f(biA[u]); bi1 = bf2f(biA[DH + u]);
    bi2 = bf2f(biA[2 * DH + u]); bi3 = bf2f(biA[3 * DH + u]);
  }
  const float bbbr = (j < DB) ? bf2f(bbbA[j]) : 0.f;
  const int mat = j >> 8, p = j & 255;
  const u16* fbp = (mat == 0) ? f1bA : (mat == 1) ? f2bA : (mat == 2) ? tabA : tbbA;
  const float ffb0 = bf2f(fbp[2 * p]), ffb1 = bf2f(fbp[2 * p + 1]);
  float hwr[8]; float hbr = 0.f;
  if (j < 128) {
    const int w = j >> 6, l = j & 63;
#pragma unroll
    for (int q = 0; q < 8; ++q) hwr[q] = bf2f(hWA[w * DH + q * 64 + l]);
    hbr = bf2f(hbA[w]);
  }

  if (j < DH) zin[DI + j] = 0.f;   // h0 = 0
  const u16* xrow = xw + (size_t)b * TT * DI;

  const int ks  = (j >> 8) * 144;        // Z k-slice start
  const int os  = (j & 255) * 8;         // Z output base (8 consecutive)
  const int zri = (j >> 8) * GZ + os;
  const int m_bb = j & 127, s2 = j >> 7; // BB split: 8 k-slices x 128 outputs

  __syncthreads();

  for (int t = 0; t < TT; ++t) {
    if (j < DI) { const float xv = bf2f(xrow[t * DI + j]); zin[j] = xv; vcat[j] = xv; }
    __syncthreads();                                   // (1) x staged

    // ---- Z: z = [x|h] @ WzT, 4 k-slices x 256 output-octets ----
    {
      float a0 = 0.f, a1 = 0.f, a2 = 0.f, a3 = 0.f,
            a4 = 0.f, a5 = 0.f, a6 = 0.f, a7 = 0.f;
      const u16* wp = WzT + (size_t)ks * GZ + os;
#pragma unroll 2
      for (int k = 0; k < 144; k += 4) {
        const float4 h4 = *(const float4*)(zin + ks + k);
        const uint4 w0 = *(const uint4*)(wp);
        const uint4 w1 = *(const uint4*)(wp + GZ);
        const uint4 w2 = *(const uint4*)(wp + 2 * GZ);
        const uint4 w3 = *(const uint4*)(wp + 3 * GZ);
        wp += 4 * GZ;
        fma8b(w0, h4.x, a0, a1, a2, a3, a4, a5, a6, a7);
        fma8b(w1, h4.y, a0, a1, a2, a3, a4, a5, a6, a7);
        fma8b(w2, h4.z, a0, a1, a2, a3, a4, a5, a6, a7);
        fma8b(w3, h4.w, a0, a1, a2, a3, a4, a5, a6, a7);
      }
      *(float4*)(zred + zri)     = make_float4(a0, a1, a2, a3);
      *(float4*)(zred + zri + 4) = make_float4(a4, a5, a6, a7);
    }
    __syncthreads();                                   // (2) z partials ready

    // ---- LSTM gates ----
    if (j < DH) {
      const float zi = bi0 + zred[u]          + zred[GZ + u]          + zred[2 * GZ + u]          + zred[3 * GZ + u];
      const float zg = bi1 + zred[DH + u]     + zred[GZ + DH + u]     + zred[2 * GZ + DH + u]     + zred[3 * GZ + DH + u];
      const float zf = bi2 + zred[2 * DH + u] + zred[GZ + 2 * DH + u] + zred[2 * GZ + 2 * DH + u] + zred[3 * GZ + 2 * DH + u];
      const float zo = bi3 + zred[3 * DH + u] + zred[GZ + 3 * DH + u] + zred[2 * GZ + 3 * DH + u] + zred[3 * GZ + 3 * DH + u];
      c = fmaf(c, fsig(zf + 1.f), ftanh(zi) * fsig(zg));
      vcat[DI + u] = ftanh(c) * fsig(zo);
    }
    __syncthreads();                                   // (3) h_lstm ready

    // ---- backbone partials: 8 k-slices of 72 ----
    {
      float acc = 0.f, acc2 = 0.f;
      const u32* bp = bbT + (s2 * 36) * DB + m_bb;
      const float* vp = vcat + s2 * 72;
#pragma unroll 3
      for (int q = 0; q < 18; ++q) {
        const float4 v4 = *(const float4*)(vp + 4 * q);
        const u32 w0 = bp[(2 * q) * DB];
        const u32 w1 = bp[(2 * q + 1) * DB];
        acc  = fmaf(blo(w0), v4.x, acc);  acc  = fmaf(bhi(w0), v4.y, acc);
        acc2 = fmaf(blo(w1), v4.z, acc2); acc2 = fmaf(bhi(w1), v4.w, acc2);
      }
      bbred[s2 * DB + m_bb] = acc + acc2;
    }
    __syncthreads();                                   // (4) bb partials
    if (j < DB) {
      float s = bbbr;
#pragma unroll
      for (int q = 0; q < 8; ++q) s += bbred[q * DB + j];
      Fb[j] = 1.7159f * ftanh(0.666f * s);
    }
    __syncthreads();                                   // (5) F ready

    // ---- ff1/ff2/ta/tb: thread owns (mat, outputs 2p,2p+1) ----
    {
      float a0 = 0.f, a1 = 0.f;
      const u16* fp = ffT + mat * (DB * DH) + 2 * p;
#pragma unroll 4
      for (int k = 0; k < DB; k += 4) {
        const float4 F4 = *(const float4*)(Fb + k);
        const u32 w0 = *(const u32*)(fp + (k + 0) * DH);
        const u32 w1 = *(const u32*)(fp + (k + 1) * DH);
        const u32 w2 = *(const u32*)(fp + (k + 2) * DH);
        const u32 w3 = *(const u32*)(fp + (k + 3) * DH);
        a0 = fmaf(blo(w0), F4.x, a0); a1 = fmaf(bhi(w0), F4.x, a1);
        a0 = fmaf(blo(w1), F4.y, a0); a1 = fmaf(bhi(w1), F4.y, a1);
        a0 = fmaf(blo(w2), F4.z, a0); a1 = fmaf(bhi(w2), F4.z, a1);
        a0 = fmaf(blo(w3), F4.w, a0); a1 = fmaf(bhi(w3), F4.w, a1);
      }
      zff[mat * DH + 2 * p]     = a0 + ffb0;
      zff[mat * DH + 2 * p + 1] = a1 + ffb1;
    }
    __syncthreads();                                   // (6) ff outputs

    // ---- combine: h_new ----
    if (j < DH) {
      const float ff1 = ftanh(zff[u]);
      const float ff2 = ftanh(zff[DH + u]);
      const float ti  = fsig(zff[2 * DH + u] + zff[3 * DH + u]);
      zin[DI + u] = fmaf(ff1, 1.f - ti, ti * ff2);
    }
    __syncthreads();                                   // (7) h_new ready

    // ---- head (2 outputs, waves 0/1) ----
    if (j < 128) {
      const int l = j & 63;
      float acc = 0.f;
#pragma unroll
      for (int q = 0; q < 8; ++q) acc = fmaf(zin[DI + q * 64 + l], hwr[q], acc);
#pragma unroll
      for (int off = 32; off > 0; off >>= 1) acc += __shfl_down(acc, off, 64);
      if (l == 0) out[((size_t)b * TT + t) * 2 + (j >> 6)] = acc + hbr;
    }
  }

  if (j < DH) out[(size_t)NB * TT * 2 + (size_t)b * DH + j] = zin[DI + j];
}

// ---------------- fallback (round-3 verified path, d_in as bf16) ----------------
__device__ __forceinline__ void fma8(float& acc, const uint4 u, const float* v) {
  acc = fmaf(blo(u.x), v[0], acc); acc = fmaf(bhi(u.x), v[1], acc);
  acc = fmaf(blo(u.y), v[2], acc); acc = fmaf(bhi(u.y), v[3], acc);
  acc = fmaf(blo(u.z), v[4], acc); acc = fmaf(bhi(u.z), v[5], acc);
  acc = fmaf(blo(u.w), v[6], acc); acc = fmaf(bhi(u.w), v[7], acc);
}
__global__ __launch_bounds__(256, 1)
void fb_scan(const u16* __restrict__ x,   const u16* __restrict__ Wi,
             const u16* __restrict__ bi,  const u16* __restrict__ Wh,
             const u16* __restrict__ bbW, const u16* __restrict__ bbb,
             const u16* __restrict__ f1W, const u16* __restrict__ f1b,
             const u16* __restrict__ f2W, const u16* __restrict__ f2b,
             const u16* __restrict__ taW, const u16* __restrict__ tab,
             const u16* __restrict__ tbW, const u16* __restrict__ tbb,
             const u16* __restrict__ hW,  const u16* __restrict__ hb,
             float* __restrict__ out)
{
  __shared__ __align__(16) float vcat[DI + DH];
  __shared__ __align__(16) float Fb2[DB];
  __shared__ __align__(16) float fpart[256];
  const int j = threadIdx.x, b = blockIdx.x;
  const int u0 = j, u1 = j + 256;
  float bi_r[8];
#pragma unroll
  for (int k = 0; k < 8; ++k) bi_r[k] = bf2f(bi[j + 256 * k]);
  const float b_f1_0 = bf2f(f1b[u0]), b_f1_1 = bf2f(f1b[u1]);
  const float b_f2_0 = bf2f(f2b[u0]), b_f2_1 = bf2f(f2b[u1]);
  const float b_ta_0 = bf2f(tab[u0]), b_ta_1 = bf2f(tab[u1]);
  const float b_tb_0 = bf2f(tbb[u0]), b_tb_1 = bf2f(tbb[u1]);
  const float b_bb = (j < DB) ? bf2f(bbb[j]) : 0.f;
  float hwr[8]; float hbr = 0.f;
  if (j < 128) {
    const int w = j >> 6, l = j & 63;
#pragma unroll
    for (int q = 0; q < 8; ++q) hwr[q] = bf2f(hW[w * DH + q * 64 + l]);
    hbr = bf2f(hb[w]);
  }
  __shared__ __align__(16) float hprev[DH];
  float c0 = 0.f, c1 = 0.f;
  hprev[u0] = 0.f; hprev[u1] = 0.f;
  const u16* xp = x + (size_t)b * TT * DI;
  __syncthreads();
  for (int t = 0; t < TT; ++t) {
    if (j < DI) vcat[j] = bf2f(xp[t * DI + j]);
    __syncthreads();
    float a[8];
#pragma unroll
    for (int k = 0; k < 8; ++k) a[k] = bi_r[k];
#pragma unroll
    for (int r = 0; r < 8; ++r) {
      const u16* wr = Wi + ((size_t)(j + 256 * r)) * DI;
      float acc = a[r];
#pragma unroll
      for (int kk = 0; kk < DI; kk += 8) fma8(acc, *(const uint4*)(wr + kk), vcat + kk);
      a[r] = acc;
    }
#pragma unroll 1
    for (int kb = 0; kb < DH; kb += 64) {
      float hreg[64];
#pragma unroll
      for (int q = 0; q < 16; ++q)
        *(float4*)(hreg + 4 * q) = *(const float4*)(hprev + kb + 4 * q);
#pragma unroll
      for (int r = 0; r < 8; ++r) {
        const u16* wr = Wh + ((size_t)(j + 256 * r)) * DH + kb;
        float acc = a[r];
#pragma unroll
        for (int cc = 0; cc < 8; ++cc) fma8(acc, *(const uint4*)(wr + 8 * cc), hreg + 8 * cc);
        a[r] = acc;
      }
    }
    {
      const float cn0 = fmaf(c0, fsig(a[4] + 1.f), ftanh(a[0]) * fsig(a[2]));
      const float cn1 = fmaf(c1, fsig(a[5] + 1.f), ftanh(a[1]) * fsig(a[3]));
      c0 = cn0; c1 = cn1;
      vcat[DI + u0] = ftanh(cn0) * fsig(a[6]);
      vcat[DI + u1] = ftanh(cn1) * fsig(a[7]);
    }
    __syncthreads();
    {
      const int m = j & (DB - 1), pp = j >> 7;
      const u16* br = bbW + (size_t)m * KZ + pp * 288;
      const float* vs = vcat + pp * 288;
      float s0 = 0.f, s1 = 0.f, s2 = 0.f, s3 = 0.f;
#pragma unroll
      for (int kk = 0; kk < 288; kk += 32) {
        fma8(s0, *(const uint4*)(br + kk), vs + kk);
        fma8(s1, *(const uint4*)(br + kk + 8), vs + kk + 8);
        fma8(s2, *(const uint4*)(br + kk + 16), vs + kk + 16);
        fma8(s3, *(const uint4*)(br + kk + 24), vs + kk + 24);
      }
      fpart[j] = (s0 + s1) + (s2 + s3);
    }
    __syncthreads();
    if (j < DB) Fb2[j] = 1.7159f * ftanh(0.666f * (b_bb + fpart[j] + fpart[j + DB]));
    __syncthreads();
    {
      float Fr[DB];
#pragma unroll
      for (int q = 0; q < 32; ++q) *(float4*)(Fr + 4 * q) = *(const float4*)(Fb2 + 4 * q);
      const u16* rp[8] = {
        f1W + (size_t)u0 * DB, f1W + (size_t)u1 * DB,
        f2W + (size_t)u0 * DB, f2W + (size_t)u1 * DB,
        taW + (size_t)u0 * DB, taW + (size_t)u1 * DB,
        tbW + (size_t)u0 * DB, tbW + (size_t)u1 * DB };
      float sacc[8] = { b_f1_0, b_f1_1, b_f2_0, b_f2_1, b_ta_0, b_ta_1, b_tb_0, b_tb_1 };
#pragma unroll
      for (int rr = 0; rr < 8; ++rr) {
        float acc = sacc[rr];
        const u16* r = rp[rr];
#pragma unroll
        for (int kk = 0; kk < DB; kk += 8) fma8(acc, *(const uint4*)(r + kk), Fr + kk);
        sacc[rr] = acc;
      }
      const float ti0 = fsig(sacc[4] + sacc[6]);
      const float ti1 = fsig(sacc[5] + sacc[7]);
      hprev[u0] = fmaf(ftanh(sacc[0]), 1.f - ti0, ti0 * ftanh(sacc[2]));
      hprev[u1] = fmaf(ftanh(sacc[1]), 1.f - ti1, ti1 * ftanh(sacc[3]));
    }
    __syncthreads();
    if (j < 128) {
      const int l = j & 63;
      float acc = 0.f;
#pragma unroll
      for (int q = 0; q < 8; ++q) acc = fmaf(hprev[q * 64 + l], hwr[q], acc);
#pragma unroll
      for (int off = 32; off > 0; off >>= 1) acc += __shfl_down(acc, off, 64);
      if (l == 0) out[((size_t)b * TT + t) * 2 + (j >> 6)] = acc + hbr;
    }
  }
  out[(size_t)NB * TT * 2 + (size_t)b * DH + u0] = hprev[u0];
  out[(size_t)NB * TT * 2 + (size_t)b * DH + u1] = hprev[u1];
}

extern "C" void kernel_launch(void* const* d_in, const int* in_sizes, int n_in,
                              void* d_out, int out_size, void* d_ws, size_t ws_size,
                              hipStream_t stream) {
  (void)in_sizes; (void)n_in; (void)out_size;

  if (ws_size >= WS_NEED) {
    char* ws = (char*)d_ws;
    int* flag = (int*)ws;
    detect_kernel<<<dim3(1), dim3(64), 0, stream>>>(
        (const u16*)d_in[0], (const u16*)d_in[1], (const u16*)d_in[3], flag);

    CopyArgs a;
    const int srcIdx[9] = {0, 2, 5, 7, 9, 11, 13, 14, 15};
    const u32 offs[9]   = {O_X, O_BI, O_BBB, O_F1B, O_F2B, O_TAB, O_TBB, O_HW, O_HB};
    const u32 ns[9]     = {NB * TT * DI, 4 * DH, DB, DH, DH, DH, DH, 2 * DH, 2};
    for (int i = 0; i < 9; ++i) {
      a.src[i] = d_in[srcIdx[i]];
      a.dst[i] = (u16*)(ws + offs[i]);
      a.n[i]   = ns[i];
    }
    conv_kernel<<<dim3(2048, 9), dim3(256), 0, stream>>>(a, flag);
    t_wz<<<dim3(8, KZ), dim3(256), 0, stream>>>(d_in[1], d_in[3], flag, (u16*)(ws + O_WZT));
    t_bb<<<dim3(288), dim3(128), 0, stream>>>(d_in[4], flag, (u32*)(ws + O_BBT));
    t_ff<<<dim3(2, DB, 4), dim3(256), 0, stream>>>(d_in[6], d_in[8], d_in[10], d_in[12],
                                                   flag, (u16*)(ws + O_FFT));
    scan_main<<<dim3(NB), dim3(NT), 0, stream>>>(
        (const u16*)(ws + O_X),   (const u16*)(ws + O_WZT),
        (const u32*)(ws + O_BBT), (const u16*)(ws + O_FFT),
        (const u16*)(ws + O_BI),  (const u16*)(ws + O_BBB),
        (const u16*)(ws + O_F1B), (const u16*)(ws + O_F2B),
        (const u16*)(ws + O_TAB), (const u16*)(ws + O_TBB),
        (const u16*)(ws + O_HW),  (const u16*)(ws + O_HB),
        (float*)d_out);
  } else {
    fb_scan<<<dim3(NB), dim3(256), 0, stream>>>(
        (const u16*)d_in[0],  (const u16*)d_in[1],  (const u16*)d_in[2],
        (const u16*)d_in[3],  (const u16*)d_in[4],  (const u16*)d_in[5],
        (const u16*)d_in[6],  (const u16*)d_in[7],  (const u16*)d_in[8],
        (const u16*)d_in[9],  (const u16*)d_in[10], (const u16*)d_in[11],
        (const u16*)d_in[12], (const u16*)d_in[13], (const u16*)d_in[14],
        (const u16*)d_in[15], (float*)d_out);
  }
}